// Round 4
// baseline (1500.234 us; speedup 1.0000x reference)
//
#include <hip/hip_runtime.h>

#define NPROJ 360
#define DH 512
#define DW 512
#define VZ 128
#define VY 128
#define VX 128
#define ZC 4   // z-values per thread (halved from 8 to double wave count)

// 4-byte-aligned float2 so the compiler emits global_load_dwordx2 at align 4
// (legal & fast on gfx9+ global address space).
typedef float f2_u __attribute__((ext_vector_type(2), aligned(4)));

__global__ __launch_bounds__(256, 8)
void cone_bp_kernel(const float* __restrict__ sino,     // [NPROJ, DH, DW]
                    const float* __restrict__ origin,   // [3] (z,y,x)
                    const float* __restrict__ spacing,  // [3] (z,y,x)
                    const float* __restrict__ traj,     // [NPROJ, 3, 4]
                    const float* __restrict__ pm_p,     // [1]
                    float* __restrict__ out)            // [VZ, VY, VX]
{
    // Grid decode (2048 blocks): bid&7 selects a z-slab (16 z's) so consecutive
    // blockIdx (round-robin across the 8 XCDs) pin each XCD's L2 to one v-band.
    // 2048 blocks = 8 blocks/CU = 32 waves/CU (VGPR=28 allows it) — Round-2
    // counters showed VALUBusy 49% / Occupancy 40%: latency-bound, so double
    // the resident waves to hide the gather latency.
    const int bid  = blockIdx.x;
    const int slab = bid & 7;           // z-slab -> XCD
    const int rem  = bid >> 3;          // 0..255
    const int zis  = rem & 3;           // which ZC-chunk inside the slab
    const int xy   = rem >> 2;          // 0..63
    const int bx   = xy & 7;            // x-tile 0..7  -> x0 = bx*16
    const int by   = xy >> 3;           // y-tile 0..7  -> y0 = by*16

    // Lane decode: 8x8 (x,y) tile per wave, 2x2 waves -> 16x16 block tile.
    // Keeps the wave's detector footprint compact at every orbit angle
    // (u-span <= ~45 px, v-span <= ~10 rows) -> few L1 lines per gather.
    const int t    = threadIdx.x;       // 0..255
    const int w    = t >> 6;            // wave 0..3
    const int l    = t & 63;            // lane 0..63
    const int x    = bx * 16 + ((w & 1) << 3) + (l & 7);
    const int y    = by * 16 + ((w >> 1) << 3) + (l >> 3);
    const int z0   = slab * 16 + zis * ZC;

    const float oz = origin[0], oy = origin[1], ox = origin[2];
    const float sz = spacing[0], sy = spacing[1], sx = spacing[2];
    const float pm = pm_p[0];

    const float wx  = ox + sx * (float)x;
    const float wy  = oy + sy * (float)y;
    const float wz0 = oz + sz * (float)z0;

    float acc[ZC];
#pragma unroll
    for (int j = 0; j < ZC; ++j) acc[j] = 0.0f;

    const float* P = traj;
    const float* img = sino;
    for (int n = 0; n < NPROJ; ++n, P += 12, img += DH * DW) {
        const float p00 = P[0], p01 = P[1], p02 = P[2],  p03 = P[3];
        const float p10 = P[4], p11 = P[5], p12 = P[6],  p13 = P[7];
        const float p20 = P[8], p21 = P[9], p22 = P[10], p23 = P[11];

        float un = p00 * wx + p01 * wy + p02 * wz0 + p03;
        float vn = p10 * wx + p11 * wy + p12 * wz0 + p13;
        float tt = p20 * wx + p21 * wy + p22 * wz0 + p23;

        if (p02 == 0.0f && p22 == 0.0f) {
            // Circular-orbit fast path: u and 1/t^2 z-independent; v linear in z.
            const float rt = 1.0f / tt;
            const float u  = un * rt;
            const float wgt = pm * rt * rt;
            const bool uval = (u >= 0.0f) && (u <= (float)(DW - 1));
            const float u0f = floorf(u);
            const float fu  = u - u0f;
            const int   u0  = (int)u0f;
            const int u0c = min(max(u0, 0), DW - 1);
            const int u1c = min(max(u0 + 1, 0), DW - 1);
            const int uc  = min(max(u0, 0), DW - 2);   // float2 load column
            const bool s0 = (u0c == uc);               // t00 from .x ?
            const bool s1 = (u1c == uc);               // t01 from .x ?
            const float dvn = p12 * sz;                // vn step per z voxel

            f2_u  pr0[ZC], pr1[ZC];
            float fv[ZC];
            bool  valid[ZC];
            // Phase 1: issue all 2*ZC packed gathers (max MLP).
#pragma unroll
            for (int j = 0; j < ZC; ++j) {
                const float v = fmaf((float)j, dvn, vn) * rt;  // 1 rounding per z
                const float v0f = floorf(v);
                fv[j] = v - v0f;
                const int v0 = (int)v0f;
                valid[j] = uval && (v >= 0.0f) && (v <= (float)(DH - 1));
                const int v0c = min(max(v0, 0), DH - 1);
                const int v1c = min(max(v0 + 1, 0), DH - 1);
                pr0[j] = *(const f2_u*)(img + v0c * DW + uc);
                pr1[j] = *(const f2_u*)(img + v1c * DW + uc);
            }
            // Phase 2: combine.
#pragma unroll
            for (int j = 0; j < ZC; ++j) {
                const float t00 = s0 ? pr0[j].x : pr0[j].y;
                const float t01 = s1 ? pr0[j].x : pr0[j].y;
                const float t10 = s0 ? pr1[j].x : pr1[j].y;
                const float t11 = s1 ? pr1[j].x : pr1[j].y;
                const float top = t00 + fu * (t01 - t00);
                const float bot = t10 + fu * (t11 - t10);
                const float s   = top + fv[j] * (bot - top);
                acc[j] += valid[j] ? (s * wgt) : 0.0f;
            }
        } else {
            // Generic path (not taken for circular trajectory; correctness fallback).
            const float dun = p02 * sz, dvn = p12 * sz, dtt = p22 * sz;
#pragma unroll
            for (int j = 0; j < ZC; ++j) {
                const float jf = (float)j;
                const float unj = fmaf(jf, dun, un);
                const float vnj = fmaf(jf, dvn, vn);
                const float ttj = fmaf(jf, dtt, tt);
                const float rt = 1.0f / ttj;
                const float u = unj * rt;
                const float v = vnj * rt;
                const float wgt = pm * rt * rt;
                const bool valid = (u >= 0.0f) && (u <= (float)(DW - 1)) &&
                                   (v >= 0.0f) && (v <= (float)(DH - 1));
                const float u0f = floorf(u), v0f = floorf(v);
                const float fu = u - u0f, fv = v - v0f;
                const int u0 = (int)u0f, v0 = (int)v0f;
                const int u0c = min(max(u0, 0), DW - 1);
                const int u1c = min(max(u0 + 1, 0), DW - 1);
                const int v0c = min(max(v0, 0), DH - 1);
                const int v1c = min(max(v0 + 1, 0), DH - 1);
                const float* r0 = img + v0c * DW;
                const float* r1 = img + v1c * DW;
                const float t00 = r0[u0c], t01 = r0[u1c];
                const float t10 = r1[u0c], t11 = r1[u1c];
                const float top = t00 + fu * (t01 - t00);
                const float bot = t10 + fu * (t11 - t10);
                const float s   = top + fv * (bot - top);
                acc[j] += valid ? (s * wgt) : 0.0f;
            }
        }
    }

#pragma unroll
    for (int j = 0; j < ZC; ++j) {
        out[((size_t)(z0 + j) * VY + y) * VX + x] = acc[j];
    }
}

extern "C" void kernel_launch(void* const* d_in, const int* in_sizes, int n_in,
                              void* d_out, int out_size, void* d_ws, size_t ws_size,
                              hipStream_t stream) {
    const float* sino    = (const float*)d_in[0];
    const float* origin  = (const float*)d_in[2];
    const float* spacing = (const float*)d_in[3];
    const float* traj    = (const float*)d_in[4];
    const float* pm      = (const float*)d_in[5];
    float* out = (float*)d_out;

    dim3 block(256, 1, 1);
    dim3 grid(2048, 1, 1);   // 8 blocks/CU -> 32 waves/CU; kernel decodes x/y/z + XCD swizzle
    cone_bp_kernel<<<grid, block, 0, stream>>>(sino, origin, spacing, traj, pm, out);
}

// Round 5
// 1468.426 us; speedup vs baseline: 1.0217x; 1.0217x over previous
//
#include <hip/hip_runtime.h>

#define NPROJ 360
#define DH 512
#define DW 512
#define VZ 128
#define VY 128
#define VX 128
#define ZC 8      // z-values per thread
#define LROWS 60  // LDS window rows (worst-case span ~53 incl. pads)
#define LPITCH 132 // row pitch in floats: 132 = 4 (mod 32) -> de-conflicted banks
#define LCOLS 128 // staged data cols per row

typedef float f2_u __attribute__((ext_vector_type(2), aligned(4)));
typedef float f4_u __attribute__((ext_vector_type(4), aligned(4)));
typedef float f4_a __attribute__((ext_vector_type(4), aligned(16)));

__global__ __launch_bounds__(256, 4)
void cone_bp_kernel(const float* __restrict__ sino,     // [NPROJ, DH, DW]
                    const float* __restrict__ origin,   // [3] (z,y,x)
                    const float* __restrict__ spacing,  // [3] (z,y,x)
                    const float* __restrict__ traj,     // [NPROJ, 3, 4]
                    const float* __restrict__ pm_p,     // [1]
                    float* __restrict__ out)            // [VZ, VY, VX]
{
    // LDS: detector window (staged per projection) + per-projection metadata.
    __shared__ __align__(16) float win[LROWS * LPITCH];   // 31,680 B
    __shared__ unsigned meta[NPROJ];                      //  1,440 B

    // Grid decode (1024 blocks, R2 config): bid&7 -> z-slab -> XCD L2 v-band.
    const int bid  = blockIdx.x;
    const int slab = bid & 7;
    const int rem  = bid >> 3;          // 0..127
    const int zis  = rem & 1;           // ZC-chunk inside slab
    const int xy   = rem >> 1;          // 0..63
    const int bx   = xy & 7;            // x-tile -> x0 = bx*16
    const int by   = xy >> 3;           // y-tile -> y0 = by*16

    // Lane decode: 8x8 (x,y) per wave, 2x2 waves -> 16x16 tile (compact footprint).
    const int t    = threadIdx.x;
    const int w    = t >> 6;
    const int l    = t & 63;
    const int x    = bx * 16 + ((w & 1) << 3) + (l & 7);
    const int y    = by * 16 + ((w >> 1) << 3) + (l >> 3);
    const int z0   = slab * 16 + zis * ZC;   // block-uniform

    const float oz = origin[0], oy = origin[1], ox = origin[2];
    const float sz = spacing[0], sy = spacing[1], sx = spacing[2];
    const float pm = pm_p[0];

    const float wx  = ox + sx * (float)x;
    const float wy  = oy + sy * (float)y;
    const float wz0 = oz + sz * (float)z0;

    // Block AABB corners (world xy; z handled via v's linearity in z).
    const float bwx0 = ox + sx * (float)(bx * 16);
    const float bwx1 = ox + sx * (float)(bx * 16 + 15);
    const float bwy0 = oy + sy * (float)(by * 16);
    const float bwy1 = oy + sy * (float)(by * 16 + 15);

    // ---- Per-projection window metadata (computed once, distributed over threads).
    // u,v are Mobius along each axis => monotone => corner hull is the exact range;
    // +/-1 px pad absorbs fp-contraction differences vs the inner-loop evaluation.
    for (int p = t; p < NPROJ; p += 256) {
        const float* Pp = traj + 12 * p;
        const float p00 = Pp[0], p01 = Pp[1], p02 = Pp[2],  p03 = Pp[3];
        const float p10 = Pp[4], p11 = Pp[5], p12 = Pp[6],  p13 = Pp[7];
        const float p20 = Pp[8], p21 = Pp[9], p22 = Pp[10], p23 = Pp[11];
        unsigned m;
        if (p02 == 0.0f && p22 == 0.0f) {
            const float dvn = p12 * sz;
            float umin = 1e30f, umax = -1e30f, vmin = 1e30f, vmax = -1e30f;
            float tmin = 1e30f;
#pragma unroll
            for (int ci = 0; ci < 4; ++ci) {
                const float cx = (ci & 1) ? bwx1 : bwx0;
                const float cy = (ci & 2) ? bwy1 : bwy0;
                const float un = p00 * cx + p01 * cy + p02 * wz0 + p03;
                const float vn = p10 * cx + p11 * cy + p12 * wz0 + p13;
                const float tt = p20 * cx + p21 * cy + p22 * wz0 + p23;
                const float rt = 1.0f / tt;
                const float uu  = un * rt;
                const float va  = vn * rt;
                const float vb  = fmaf((float)(ZC - 1), dvn, vn) * rt;
                tmin = fminf(tmin, tt);
                umin = fminf(umin, uu); umax = fmaxf(umax, uu);
                vmin = fminf(vmin, fminf(va, vb));
                vmax = fmaxf(vmax, fmaxf(va, vb));
            }
            const bool skip = (umax < -0.5f) || (umin > (float)(DW - 1) + 0.5f) ||
                              (vmax < -0.5f) || (vmin > (float)(DH - 1) + 0.5f);
            const int r_lo = min(max((int)floorf(vmin) - 1, 0), DH - 1);
            const int r_hi = min(max((int)floorf(vmax) + 2, 0), DH - 1);
            const int rows = r_hi - r_lo + 1;
            const int c_lo = min(max((int)floorf(umin) - 1, 0), DW - 2);
            const int c_hi = min(max((int)floorf(umax) + 2, 0), DW - 1);
            const int cols = c_hi - c_lo + 1;
            const bool fb = (tmin <= 0.0f) || (rows > LROWS) || (cols > LCOLS);
            m = (unsigned)r_lo | ((unsigned)c_lo << 9) |
                ((unsigned)min(rows, 127) << 18) |
                (skip ? (1u << 25) : 0u) | (fb ? (1u << 26) : 0u);
        } else {
            m = (1u << 26);   // non-circular: fallback (global-gather) path
        }
        meta[p] = m;
    }
    __syncthreads();

    float acc[ZC];
#pragma unroll
    for (int j = 0; j < ZC; ++j) acc[j] = 0.0f;

    const float* P = traj;
    const float* img = sino;
    for (int n = 0; n < NPROJ; ++n, P += 12, img += DH * DW) {
        const unsigned m = meta[n];
        const bool skip = (m >> 25) & 1u;
        const bool fb   = (m >> 26) & 1u;
        const int r_lo  = m & 511;
        const int c_lo  = (m >> 9) & 511;
        const int rows  = (m >> 18) & 127;

        __syncthreads();   // prev iteration's LDS reads complete before restage
        if (!skip && !fb) {
            if (n != NPROJ - 1) {
                // dwordx4 staging; col overrun reads next-row bytes (valid memory,
                // lands in never-sampled junk cols). Only the last projection could
                // run past the buffer end -> scalar-clamped path below.
                const int nch = rows << 5;          // rows * 32 chunks
                for (int c = t; c < nch; c += 256) {
                    const int r  = c >> 5;
                    const int c4 = (c & 31) << 2;
                    const f4_u vq = *(const f4_u*)(img + (r_lo + r) * DW + (c_lo + c4));
                    *(f4_a*)(&win[r * LPITCH + c4]) = vq;
                }
            } else {
                const int nel = rows << 7;          // rows * 128 elems
                for (int c = t; c < nel; c += 256) {
                    const int r  = c >> 7;
                    const int cc = c & 127;
                    const int gc = min(c_lo + cc, DW - 1);
                    win[r * LPITCH + cc] = img[(r_lo + r) * DW + gc];
                }
            }
        }
        __syncthreads();   // staged window visible
        if (skip) continue;

        const float p00 = P[0], p01 = P[1], p02 = P[2],  p03 = P[3];
        const float p10 = P[4], p11 = P[5], p12 = P[6],  p13 = P[7];
        const float p20 = P[8], p21 = P[9], p22 = P[10], p23 = P[11];

        float un = p00 * wx + p01 * wy + p02 * wz0 + p03;
        float vn = p10 * wx + p11 * wy + p12 * wz0 + p13;
        float tt = p20 * wx + p21 * wy + p22 * wz0 + p23;

        if (!fb) {
            // Circular fast path, sampling from LDS (bit-identical math to R2).
            const float rt = 1.0f / tt;
            const float u  = un * rt;
            const float wgt = pm * rt * rt;
            const bool uval = (u >= 0.0f) && (u <= (float)(DW - 1));
            const float u0f = floorf(u);
            const float fu  = u - u0f;
            const int   u0  = (int)u0f;
            const int u0c = min(max(u0, 0), DW - 1);
            const int u1c = min(max(u0 + 1, 0), DW - 1);
            const int uc  = min(max(u0, 0), DW - 2);
            const bool s0 = (u0c == uc);
            const bool s1 = (u1c == uc);
            const float dvn = p12 * sz;
            const int cbase = (uc - c_lo) - r_lo * LPITCH;

            float t00[ZC], t01[ZC], t10[ZC], t11[ZC], fv[ZC];
            bool  valid[ZC];
            // Phase 1: issue all LDS reads (ds_read2_b32 pairs).
#pragma unroll
            for (int j = 0; j < ZC; ++j) {
                const float v = fmaf((float)j, dvn, vn) * rt;
                const float v0f = floorf(v);
                fv[j] = v - v0f;
                const int v0 = (int)v0f;
                valid[j] = uval && (v >= 0.0f) && (v <= (float)(DH - 1));
                const int v0c = min(max(v0, 0), DH - 1);
                const int v1c = min(v0c + 1, DH - 1);
                const int a0 = v0c * LPITCH + cbase;
                const int a1 = v1c * LPITCH + cbase;
                t00[j] = win[a0]; t01[j] = win[a0 + 1];
                t10[j] = win[a1]; t11[j] = win[a1 + 1];
            }
            // Phase 2: combine.
#pragma unroll
            for (int j = 0; j < ZC; ++j) {
                const float q00 = s0 ? t00[j] : t01[j];
                const float q01 = s1 ? t00[j] : t01[j];
                const float q10 = s0 ? t10[j] : t11[j];
                const float q11 = s1 ? t10[j] : t11[j];
                const float top = q00 + fu * (q01 - q00);
                const float bot = q10 + fu * (q11 - q10);
                const float s   = top + fv[j] * (bot - top);
                acc[j] += valid[j] ? (s * wgt) : 0.0f;
            }
        } else if (p02 == 0.0f && p22 == 0.0f) {
            // Fallback: circular-orbit global-gather path (R2 kernel, proven).
            const float rt = 1.0f / tt;
            const float u  = un * rt;
            const float wgt = pm * rt * rt;
            const bool uval = (u >= 0.0f) && (u <= (float)(DW - 1));
            const float u0f = floorf(u);
            const float fu  = u - u0f;
            const int   u0  = (int)u0f;
            const int u0c = min(max(u0, 0), DW - 1);
            const int u1c = min(max(u0 + 1, 0), DW - 1);
            const int uc  = min(max(u0, 0), DW - 2);
            const bool s0 = (u0c == uc);
            const bool s1 = (u1c == uc);
            const float dvn = p12 * sz;

            f2_u  pr0[ZC], pr1[ZC];
            float fv[ZC];
            bool  valid[ZC];
#pragma unroll
            for (int j = 0; j < ZC; ++j) {
                const float v = fmaf((float)j, dvn, vn) * rt;
                const float v0f = floorf(v);
                fv[j] = v - v0f;
                const int v0 = (int)v0f;
                valid[j] = uval && (v >= 0.0f) && (v <= (float)(DH - 1));
                const int v0c = min(max(v0, 0), DH - 1);
                const int v1c = min(max(v0 + 1, 0), DH - 1);
                pr0[j] = *(const f2_u*)(img + v0c * DW + uc);
                pr1[j] = *(const f2_u*)(img + v1c * DW + uc);
            }
#pragma unroll
            for (int j = 0; j < ZC; ++j) {
                const float q00 = s0 ? pr0[j].x : pr0[j].y;
                const float q01 = s1 ? pr0[j].x : pr0[j].y;
                const float q10 = s0 ? pr1[j].x : pr1[j].y;
                const float q11 = s1 ? pr1[j].x : pr1[j].y;
                const float top = q00 + fu * (q01 - q00);
                const float bot = q10 + fu * (q11 - q10);
                const float s   = top + fv[j] * (bot - top);
                acc[j] += valid[j] ? (s * wgt) : 0.0f;
            }
        } else {
            // Generic trajectory fallback (correctness only).
            const float dun = p02 * sz, dvn = p12 * sz, dtt = p22 * sz;
#pragma unroll
            for (int j = 0; j < ZC; ++j) {
                const float jf = (float)j;
                const float unj = fmaf(jf, dun, un);
                const float vnj = fmaf(jf, dvn, vn);
                const float ttj = fmaf(jf, dtt, tt);
                const float rt = 1.0f / ttj;
                const float u = unj * rt;
                const float v = vnj * rt;
                const float wgt = pm * rt * rt;
                const bool valid = (u >= 0.0f) && (u <= (float)(DW - 1)) &&
                                   (v >= 0.0f) && (v <= (float)(DH - 1));
                const float u0f = floorf(u), v0f = floorf(v);
                const float fu = u - u0f, fv = v - v0f;
                const int u0 = (int)u0f, v0 = (int)v0f;
                const int u0c = min(max(u0, 0), DW - 1);
                const int u1c = min(max(u0 + 1, 0), DW - 1);
                const int v0c = min(max(v0, 0), DH - 1);
                const int v1c = min(max(v0 + 1, 0), DH - 1);
                const float* r0 = img + v0c * DW;
                const float* r1 = img + v1c * DW;
                const float t00 = r0[u0c], t01 = r0[u1c];
                const float t10 = r1[u0c], t11 = r1[u1c];
                const float top = t00 + fu * (t01 - t00);
                const float bot = t10 + fu * (t11 - t10);
                const float s   = top + fv * (bot - top);
                acc[j] += valid ? (s * wgt) : 0.0f;
            }
        }
    }

#pragma unroll
    for (int j = 0; j < ZC; ++j) {
        out[((size_t)(z0 + j) * VY + y) * VX + x] = acc[j];
    }
}

extern "C" void kernel_launch(void* const* d_in, const int* in_sizes, int n_in,
                              void* d_out, int out_size, void* d_ws, size_t ws_size,
                              hipStream_t stream) {
    const float* sino    = (const float*)d_in[0];
    const float* origin  = (const float*)d_in[2];
    const float* spacing = (const float*)d_in[3];
    const float* traj    = (const float*)d_in[4];
    const float* pm      = (const float*)d_in[5];
    float* out = (float*)d_out;

    dim3 block(256, 1, 1);
    dim3 grid(1024, 1, 1);   // R2 config: 4 blocks/CU, ZC=8
    cone_bp_kernel<<<grid, block, 0, stream>>>(sino, origin, spacing, traj, pm, out);
}